// Round 1
// baseline (146.425 us; speedup 1.0000x reference)
//
#include <hip/hip_runtime.h>

// EmotionCaps dynamic routing (fp32 I/O):
// u: [B=64, N=1024, I=64] f32; W: [N=1024, E=8, O=32, I=64] f32
// out: v [B=64, E=8, O=32] f32
//
// Structure (5 dispatches — kernel boundaries are the only cross-block sync;
// measured dead ends: grid.sync 110us/sync (r3), 64-block fusion 87us (r6),
// threadfence+counter 190us/pass (r7)):
//   k_uhat   : u_hat bf16 via 16x16x32 bf16 MFMA; zeroes s0/s1/s2.
//   k_route 0: c=1/8            -> atomicAdd s0   (plain atomics: r2-proven)
//   k_route 1: v0=squash(s0)    -> logits=uh.v0   -> atomicAdd s1
//   k_route 2: v01=v0+v1        -> logits=uh.v01  -> atomicAdd s2
//   k_out    : out = squash(s2)
// Logit identity b2 = uh.(v0+v1) verified rounds 4-7 (absmax stable 0.0039).
//
// THIS ROUND: packed-uint2 uh layout, no LDS transpose in k_uhat.
// uh2 uint2-index = n*4096 + w*1024 + nt*256 + mt*64 + (g*16+m16)
//   where the uint2 packs r=0..3 (b = mt*16 + g*4 + r), eo = w*64+nt*16+m16.
// Store side: lane l = g*16+m16 -> 64 consecutive uint2 per store instr
//   (512 B coalesced, straight from MFMA acc regs, zero LDS, one barrier).
// Load side (route): lane l reads 2 uint4 at uint2-idx
//   (l>>4)*1024 + ((l>>2)&3)*256 + bg*16 + (l&3)*4  (bg = b>>2, 16 groups)
//   -> owns eo = 4l..4l+3 for 4 consecutive b.  IDENTITY: w*64+nt*16+mq*4
//   = 4*((l&0x30)|(l&0xC)|(l&3)) = 4l, so ALL shuffle groups (dot o: xor
//   1,2,4; softmax E: xor 8,16,32; squash4) are unchanged from the
//   verified r2-r7 math. e-group = lanes {l>>3 == const} as before.

#define B_  64
#define N_  1024
#define I_  64
#define E_  8
#define O_  32
#define EO_ 256
#define PAD_ 72

typedef __bf16 bf16x8 __attribute__((ext_vector_type(8)));
typedef __bf16 bf16x4v __attribute__((ext_vector_type(4)));
typedef float  f32x4  __attribute__((ext_vector_type(4)));

__device__ __forceinline__ float bf2f(unsigned int h) {
    unsigned int x = (h & 0xffffu) << 16;
    return __builtin_bit_cast(float, x);
}
__device__ __forceinline__ void cvt_store4(unsigned short* dst, float4 q) {
    bf16x4v v;
    v[0] = (__bf16)q.x; v[1] = (__bf16)q.y; v[2] = (__bf16)q.z; v[3] = (__bf16)q.w;
    *(bf16x4v*)dst = v;
}
__device__ __forceinline__ bf16x8 cvt8(const float* __restrict__ p) {
    float4 q0 = *(const float4*)p;
    float4 q1 = *(const float4*)(p + 4);
    bf16x8 a;
    a[0] = (__bf16)q0.x; a[1] = (__bf16)q0.y; a[2] = (__bf16)q0.z; a[3] = (__bf16)q0.w;
    a[4] = (__bf16)q1.x; a[5] = (__bf16)q1.y; a[6] = (__bf16)q1.z; a[7] = (__bf16)q1.w;
    return a;
}
// squash over the 32-elem o-group; lane l holds s[4l..4l+3] of its e-group
// (8 lanes x 4). shfl 1,2,4 stays inside the 8-lane e-group.
__device__ __forceinline__ float4 squash4(float4 s4) {
    float sq = s4.x * s4.x + s4.y * s4.y + s4.z * s4.z + s4.w * s4.w;
    sq += __shfl_xor(sq, 1);
    sq += __shfl_xor(sq, 2);
    sq += __shfl_xor(sq, 4);
    float nrm = sqrtf(sq);
    float sc = sq / ((1.f + sq) * (nrm + 1e-8f));
    return make_float4(sc * s4.x, sc * s4.y, sc * s4.z, sc * s4.w);
}

// ---------------------------------------------------------------------------
// K1: one block per n. D[64b x 256eo] = u[:,n,:] . W[n]^T via 16x16x32 bf16
// MFMA (fragment layouts verified rounds 3-7). u staged in LDS (A-frags);
// W frags streamed from global; acc stored DIRECTLY as packed uint2 in the
// uh2 layout (no Dt transpose, no 3rd barrier, LDS 9.2 KB).
// __launch_bounds__(256,4): VGPR<=128 -> 4 blocks/CU -> whole 1024-block
// grid resident in one round (acc 64 + afr 32 + staging fits ~120).
// Blocks 0..2 zero s0/s1/s2 (workspace is poisoned each call).
// ---------------------------------------------------------------------------
__global__ __launch_bounds__(256, 4) void k_uhat(const float* __restrict__ u,
                                                 const float* __restrict__ W,
                                                 uint2* __restrict__ uh,
                                                 float* __restrict__ s012) {
    const int n = blockIdx.x;
    const int t = threadIdx.x;
    const int w = t >> 6, l = t & 63;
    const int m16 = l & 15, g = l >> 4;

    if (n < 3) {
        float* sz = s012 + n * (B_ * EO_);
#pragma unroll
        for (int i = 0; i < 64; ++i) sz[i * 256 + t] = 0.f;
    }

    __shared__ __align__(16) unsigned short ul[B_ * PAD_];   // 9216 B

#pragma unroll
    for (int j = 0; j < 4; ++j) {
        int idx = j * 256 + t;
        int b = idx >> 4, c = idx & 15;
        float4 q = *(const float4*)(u + (size_t)b * (N_ * I_) + n * I_ + c * 4);
        cvt_store4(&ul[b * PAD_ + c * 4], q);
    }
    __syncthreads();

    bf16x8 afr[4][2];   // A[m=lane&15][k=(lane>>4)*8+j]
#pragma unroll
    for (int mt = 0; mt < 4; ++mt)
#pragma unroll
        for (int ks = 0; ks < 2; ++ks)
            afr[mt][ks] = *(const bf16x8*)&ul[(mt * 16 + m16) * PAD_ + ks * 32 + g * 8];

    f32x4 acc[4][4];
#pragma unroll
    for (int nt = 0; nt < 4; ++nt)
#pragma unroll
        for (int mt = 0; mt < 4; ++mt)
            acc[nt][mt] = (f32x4){0.f, 0.f, 0.f, 0.f};

    const float* Wn = W + (size_t)n * (EO_ * I_);
#pragma unroll
    for (int nt = 0; nt < 4; ++nt) {
        const int eo = w * 64 + nt * 16 + m16;
        const float* wp = Wn + (size_t)eo * I_ + g * 8;
        bf16x8 b0 = cvt8(wp);
        bf16x8 b1 = cvt8(wp + 32);
#pragma unroll
        for (int mt = 0; mt < 4; ++mt) {
            acc[nt][mt] = __builtin_amdgcn_mfma_f32_16x16x32_bf16(afr[mt][0], b0, acc[nt][mt], 0, 0, 0);
            acc[nt][mt] = __builtin_amdgcn_mfma_f32_16x16x32_bf16(afr[mt][1], b1, acc[nt][mt], 0, 0, 0);
        }
    }

    // D lane map: col=lane&15 (eo within tile), row=(lane>>4)*4+reg (b).
    // Pack the 4 reg values (r=0..3 = 4 consecutive b) into one uint2 and
    // store straight to the uh2 layout: 64 consecutive uint2 per (nt,mt).
    uint2* uhn = uh + (size_t)n * 4096 + w * 1024;
#pragma unroll
    for (int nt = 0; nt < 4; ++nt)
#pragma unroll
        for (int mt = 0; mt < 4; ++mt) {
            __bf16 h0 = (__bf16)acc[nt][mt][0];
            __bf16 h1 = (__bf16)acc[nt][mt][1];
            __bf16 h2 = (__bf16)acc[nt][mt][2];
            __bf16 h3 = (__bf16)acc[nt][mt][3];
            uint2 p;
            p.x = (unsigned)__builtin_bit_cast(unsigned short, h0)
                | ((unsigned)__builtin_bit_cast(unsigned short, h1) << 16);
            p.y = (unsigned)__builtin_bit_cast(unsigned short, h2)
                | ((unsigned)__builtin_bit_cast(unsigned short, h3) << 16);
            uhn[nt * 256 + mt * 64 + l] = p;
        }
}

// ---------------------------------------------------------------------------
// K2: one routing pass over uh2. 1024 blocks = (bg in 16, chunk of 16 n);
// wave handles 4 n serially with all 8 uint4 loads issued upfront; lane l
// owns eo = 4l..4l+3 (identity: see header) for 4 consecutive b = 4*bg+r.
// Shuffle math verified rounds 2-7 and UNCHANGED: dot over o = shfl 1,2,4;
// softmax over E = shfl 8,16,32.  LDS 4-wave reduce -> 4 atomics/thread.
// ---------------------------------------------------------------------------
__global__ __launch_bounds__(256) void k_route(const uint2* __restrict__ uh,
                                               const float* __restrict__ s0,
                                               const float* __restrict__ s1,
                                               float* __restrict__ tgt,
                                               int it) {
    const int blk = blockIdx.x;
    const int bg = blk >> 6;          // 16 b-groups (b = 4*bg + r)
    const int chunk = blk & 63;       // 64 chunks of 16 n
    const int t = threadIdx.x, wave = t >> 6, l = t & 63;

    // lane offset within one n-slab, in uint4 units (slab = 2048 uint4)
    const int laneoff = ((l >> 4) * 1024 + ((l >> 2) & 3) * 256 + bg * 16 + (l & 3) * 4) >> 1;
    const uint4* base = (const uint4*)uh;
    const int n0 = chunk * 16 + wave * 4;

    float4 vv[4];
    if (it != 0) {
        // recompute v (and v0+v1 for it==2) per b: lane's eo set is 4l..4l+3,
        // exactly the old mapping -> squash4's e-group shuffles unchanged.
#pragma unroll
        for (int r = 0; r < 4; ++r) {
            const int b = bg * 4 + r;
            float4 v4 = squash4(*(const float4*)(s0 + b * EO_ + 4 * l));
            if (it == 2) {
                float4 v1 = squash4(*(const float4*)(s1 + b * EO_ + 4 * l));
                v4.x += v1.x; v4.y += v1.y; v4.z += v1.z; v4.w += v1.w;
            }
            vv[r] = v4;
        }
    }

    uint4 LA[4][2];
#pragma unroll
    for (int nn = 0; nn < 4; ++nn) {
        const size_t nb = (size_t)(n0 + nn) * 2048 + laneoff;
        LA[nn][0] = base[nb];
        LA[nn][1] = base[nb + 1];
    }

    float acc[4][4];
#pragma unroll
    for (int r = 0; r < 4; ++r)
#pragma unroll
        for (int q = 0; q < 4; ++q) acc[r][q] = 0.f;

#pragma unroll
    for (int nn = 0; nn < 4; ++nn) {
        const uint4 L0 = LA[nn][0], L1 = LA[nn][1];
        float x[4][4];   // x[r][q] = u_hat[b=4bg+r][n][4l+q]
        x[0][0] = bf2f(L0.x); x[1][0] = bf2f(L0.x >> 16);
        x[2][0] = bf2f(L0.y); x[3][0] = bf2f(L0.y >> 16);
        x[0][1] = bf2f(L0.z); x[1][1] = bf2f(L0.z >> 16);
        x[2][1] = bf2f(L0.w); x[3][1] = bf2f(L0.w >> 16);
        x[0][2] = bf2f(L1.x); x[1][2] = bf2f(L1.x >> 16);
        x[2][2] = bf2f(L1.y); x[3][2] = bf2f(L1.y >> 16);
        x[0][3] = bf2f(L1.z); x[1][3] = bf2f(L1.z >> 16);
        x[2][3] = bf2f(L1.w); x[3][3] = bf2f(L1.w >> 16);

        float c[4];
        if (it == 0) {
            c[0] = c[1] = c[2] = c[3] = 0.125f;
        } else {
            float lg[4];
#pragma unroll
            for (int r = 0; r < 4; ++r) {
                float pd = x[r][0] * vv[r].x + x[r][1] * vv[r].y
                         + x[r][2] * vv[r].z + x[r][3] * vv[r].w;
                pd += __shfl_xor(pd, 1);
                pd += __shfl_xor(pd, 2);
                pd += __shfl_xor(pd, 4);        // logit(n, e, b=4bg+r)
                lg[r] = pd;
            }
            float mx[4];
#pragma unroll
            for (int r = 0; r < 4; ++r) mx[r] = lg[r];
#pragma unroll
            for (int r = 0; r < 4; ++r) mx[r] = fmaxf(mx[r], __shfl_xor(mx[r], 8));
#pragma unroll
            for (int r = 0; r < 4; ++r) mx[r] = fmaxf(mx[r], __shfl_xor(mx[r], 16));
#pragma unroll
            for (int r = 0; r < 4; ++r) mx[r] = fmaxf(mx[r], __shfl_xor(mx[r], 32));
            float ex[4], sm[4];
#pragma unroll
            for (int r = 0; r < 4; ++r) { ex[r] = __expf(lg[r] - mx[r]); sm[r] = ex[r]; }
#pragma unroll
            for (int r = 0; r < 4; ++r) sm[r] += __shfl_xor(sm[r], 8);
#pragma unroll
            for (int r = 0; r < 4; ++r) sm[r] += __shfl_xor(sm[r], 16);
#pragma unroll
            for (int r = 0; r < 4; ++r) sm[r] += __shfl_xor(sm[r], 32);
#pragma unroll
            for (int r = 0; r < 4; ++r) c[r] = ex[r] * __builtin_amdgcn_rcpf(sm[r]);
        }
#pragma unroll
        for (int r = 0; r < 4; ++r)
#pragma unroll
            for (int q = 0; q < 4; ++q)
                acc[r][q] = fmaf(c[r], x[r][q], acc[r][q]);
    }

    __shared__ __align__(16) float red[4][4][EO_];   // [wave][r][eo] 16 KB
#pragma unroll
    for (int r = 0; r < 4; ++r)
        *(float4*)&red[wave][r][4 * l] = make_float4(acc[r][0], acc[r][1], acc[r][2], acc[r][3]);
    __syncthreads();
#pragma unroll
    for (int r = 0; r < 4; ++r) {
        float v = red[0][r][t] + red[1][r][t] + red[2][r][t] + red[3][r][t];
        atomicAdd(&tgt[(bg * 4 + r) * EO_ + t], v);
    }
}

// ---------------------------------------------------------------------------
// K3: out = squash(s2). 64 blocks x 256 (t = eo; o-group = 32 lanes).
// ---------------------------------------------------------------------------
__global__ __launch_bounds__(256) void k_out(const float* __restrict__ s2,
                                             float* __restrict__ out) {
    const int b = blockIdx.x, t = threadIdx.x;
    float sv = s2[b * EO_ + t];
    float sq = sv * sv;
    sq += __shfl_xor(sq, 1);
    sq += __shfl_xor(sq, 2);
    sq += __shfl_xor(sq, 4);
    sq += __shfl_xor(sq, 8);
    sq += __shfl_xor(sq, 16);
    float nrm = sqrtf(sq);
    out[b * EO_ + t] = sq / ((1.f + sq) * (nrm + 1e-8f)) * sv;
}

extern "C" void kernel_launch(void* const* d_in, const int* in_sizes, int n_in,
                              void* d_out, int out_size, void* d_ws, size_t ws_size,
                              hipStream_t stream) {
    const float* u = (const float*)d_in[0];     // f32 [64,1024,64]
    const float* W = (const float*)d_in[1];     // f32 [1024,8,32,64]
    float* out = (float*)d_out;                 // f32 [64,8,32]

    char* ws = (char*)d_ws;
    uint2* uh = (uint2*)ws;                      // 33,554,432 B  u_hat bf16 (uh2 layout)
    float* s0 = (float*)(ws + 33554432);         // 65,536 B
    float* s1 = s0 + B_ * EO_;                   // contiguous s0|s1|s2 for zeroing
    float* s2 = s1 + B_ * EO_;

    k_uhat <<<dim3(N_),   dim3(256), 0, stream>>>(u, W, uh, s0);
    k_route<<<dim3(1024), dim3(256), 0, stream>>>(uh, s0, s1, s0, 0);
    k_route<<<dim3(1024), dim3(256), 0, stream>>>(uh, s0, s1, s1, 1);
    k_route<<<dim3(1024), dim3(256), 0, stream>>>(uh, s0, s1, s2, 2);
    k_out  <<<dim3(B_),   dim3(256), 0, stream>>>(s2, out);
}

// Round 2
// 141.173 us; speedup vs baseline: 1.0372x; 1.0372x over previous
//
#include <hip/hip_runtime.h>

// EmotionCaps dynamic routing (fp32 I/O):
// u: [B=64, N=1024, I=64] f32; W: [N=1024, E=8, O=32, I=64] f32
// out: v [B=64, E=8, O=32] f32
//
// Structure (5 dispatches — kernel boundaries are the only cross-block sync;
// measured dead ends: grid.sync 110us/sync (r3), 64-block fusion 87us (r6),
// threadfence+counter 190us/pass (r7)):
//   k_uhat   : u_hat bf16 via 16x16x32 bf16 MFMA; zeroes s0/s1/s2.
//   k_route 0: c=1/8            -> atomicAdd s0   (plain atomics: r2-proven)
//   k_route 1: v0=squash(s0)    -> logits=uh.v0   -> atomicAdd s1
//   k_route 2: v01=v0+v1        -> logits=uh.v01  -> atomicAdd s2
//   k_out    : out = squash(s2)
// Logit identity b2 = uh.(v0+v1) verified rounds 4-7 (absmax stable 0.0039).
//
// uh2 packed layout (correctness-verified last round, absmax 0.0039):
// uint2-index = n*4096 + w*1024 + nt*256 + mt*64 + (g*16+m16)
//   uint2 packs r=0..3 (b = mt*16 + g*4 + r) for eo = w*64+nt*16+m16.
// Store side: straight from MFMA acc regs, 512 B coalesced, zero LDS xpose.
// Load side: lane l reads 2 uint4 at uint2-idx
//   (l>>4)*1024 + ((l>>2)&3)*256 + bg*16 + (l&3)*4  -> owns eo=4l..4l+3 for
//   4 consecutive b. All verified shuffle groups unchanged (dot o: xor 1,2,4;
//   softmax E: xor 8,16,32; squash4 e-group).
//
// THIS ROUND (un-bundling last round's -11.5us regression):
//  - k_uhat: NO min-waves clamp. (256,4) forced VGPR<=128 against ~130 live
//    -> hot-loop spills suspected. Let allocator run free (round-0 regime).
//  - k_route: 512 blocks, 8 n per wave (proven count) -> atomics back to
//    524K/pass (32 adds/address), same as the proven 135us kernel.

#define B_  64
#define N_  1024
#define I_  64
#define E_  8
#define O_  32
#define EO_ 256
#define PAD_ 72

typedef __bf16 bf16x8 __attribute__((ext_vector_type(8)));
typedef __bf16 bf16x4v __attribute__((ext_vector_type(4)));
typedef float  f32x4  __attribute__((ext_vector_type(4)));

__device__ __forceinline__ float bf2f(unsigned int h) {
    unsigned int x = (h & 0xffffu) << 16;
    return __builtin_bit_cast(float, x);
}
__device__ __forceinline__ void cvt_store4(unsigned short* dst, float4 q) {
    bf16x4v v;
    v[0] = (__bf16)q.x; v[1] = (__bf16)q.y; v[2] = (__bf16)q.z; v[3] = (__bf16)q.w;
    *(bf16x4v*)dst = v;
}
__device__ __forceinline__ bf16x8 cvt8(const float* __restrict__ p) {
    float4 q0 = *(const float4*)p;
    float4 q1 = *(const float4*)(p + 4);
    bf16x8 a;
    a[0] = (__bf16)q0.x; a[1] = (__bf16)q0.y; a[2] = (__bf16)q0.z; a[3] = (__bf16)q0.w;
    a[4] = (__bf16)q1.x; a[5] = (__bf16)q1.y; a[6] = (__bf16)q1.z; a[7] = (__bf16)q1.w;
    return a;
}
// squash over the 32-elem o-group; lane l holds s[4l..4l+3] of its e-group
// (8 lanes x 4). shfl 1,2,4 stays inside the 8-lane e-group.
__device__ __forceinline__ float4 squash4(float4 s4) {
    float sq = s4.x * s4.x + s4.y * s4.y + s4.z * s4.z + s4.w * s4.w;
    sq += __shfl_xor(sq, 1);
    sq += __shfl_xor(sq, 2);
    sq += __shfl_xor(sq, 4);
    float nrm = sqrtf(sq);
    float sc = sq / ((1.f + sq) * (nrm + 1e-8f));
    return make_float4(sc * s4.x, sc * s4.y, sc * s4.z, sc * s4.w);
}

// ---------------------------------------------------------------------------
// K1: one block per n. D[64b x 256eo] = u[:,n,:] . W[n]^T via 16x16x32 bf16
// MFMA (fragment layouts verified rounds 3-7). u staged in LDS (A-frags);
// W frags streamed from global; acc stored DIRECTLY as packed uint2 in the
// uh2 layout (no Dt transpose, no 3rd barrier, LDS 9.2 KB).
// No min-waves bound: ~130+ live VGPRs, a forced 128 clamp spills (r1 lesson).
// Blocks 0..2 zero s0/s1/s2 (workspace is poisoned each call).
// ---------------------------------------------------------------------------
__global__ __launch_bounds__(256) void k_uhat(const float* __restrict__ u,
                                              const float* __restrict__ W,
                                              uint2* __restrict__ uh,
                                              float* __restrict__ s012) {
    const int n = blockIdx.x;
    const int t = threadIdx.x;
    const int w = t >> 6, l = t & 63;
    const int m16 = l & 15, g = l >> 4;

    if (n < 3) {
        float* sz = s012 + n * (B_ * EO_);
#pragma unroll
        for (int i = 0; i < 64; ++i) sz[i * 256 + t] = 0.f;
    }

    __shared__ __align__(16) unsigned short ul[B_ * PAD_];   // 9216 B

#pragma unroll
    for (int j = 0; j < 4; ++j) {
        int idx = j * 256 + t;
        int b = idx >> 4, c = idx & 15;
        float4 q = *(const float4*)(u + (size_t)b * (N_ * I_) + n * I_ + c * 4);
        cvt_store4(&ul[b * PAD_ + c * 4], q);
    }
    __syncthreads();

    bf16x8 afr[4][2];   // A[m=lane&15][k=(lane>>4)*8+j]
#pragma unroll
    for (int mt = 0; mt < 4; ++mt)
#pragma unroll
        for (int ks = 0; ks < 2; ++ks)
            afr[mt][ks] = *(const bf16x8*)&ul[(mt * 16 + m16) * PAD_ + ks * 32 + g * 8];

    f32x4 acc[4][4];
#pragma unroll
    for (int nt = 0; nt < 4; ++nt)
#pragma unroll
        for (int mt = 0; mt < 4; ++mt)
            acc[nt][mt] = (f32x4){0.f, 0.f, 0.f, 0.f};

    const float* Wn = W + (size_t)n * (EO_ * I_);
#pragma unroll
    for (int nt = 0; nt < 4; ++nt) {
        const int eo = w * 64 + nt * 16 + m16;
        const float* wp = Wn + (size_t)eo * I_ + g * 8;
        bf16x8 b0 = cvt8(wp);
        bf16x8 b1 = cvt8(wp + 32);
#pragma unroll
        for (int mt = 0; mt < 4; ++mt) {
            acc[nt][mt] = __builtin_amdgcn_mfma_f32_16x16x32_bf16(afr[mt][0], b0, acc[nt][mt], 0, 0, 0);
            acc[nt][mt] = __builtin_amdgcn_mfma_f32_16x16x32_bf16(afr[mt][1], b1, acc[nt][mt], 0, 0, 0);
        }
    }

    // D lane map: col=lane&15 (eo within tile), row=(lane>>4)*4+reg (b).
    // Pack the 4 reg values (r=0..3 = 4 consecutive b) into one uint2 and
    // store straight to the uh2 layout: 64 consecutive uint2 per (nt,mt).
    uint2* uhn = uh + (size_t)n * 4096 + w * 1024;
#pragma unroll
    for (int nt = 0; nt < 4; ++nt)
#pragma unroll
        for (int mt = 0; mt < 4; ++mt) {
            __bf16 h0 = (__bf16)acc[nt][mt][0];
            __bf16 h1 = (__bf16)acc[nt][mt][1];
            __bf16 h2 = (__bf16)acc[nt][mt][2];
            __bf16 h3 = (__bf16)acc[nt][mt][3];
            uint2 p;
            p.x = (unsigned)__builtin_bit_cast(unsigned short, h0)
                | ((unsigned)__builtin_bit_cast(unsigned short, h1) << 16);
            p.y = (unsigned)__builtin_bit_cast(unsigned short, h2)
                | ((unsigned)__builtin_bit_cast(unsigned short, h3) << 16);
            uhn[nt * 256 + mt * 64 + l] = p;
        }
}

// ---------------------------------------------------------------------------
// K2: one routing pass over uh2. 512 blocks = (bg in 16, chunk of 32 n);
// wave handles 8 n (proven round-0 count) in two 4-n load batches; lane l
// owns eo = 4l..4l+3 for 4 consecutive b = 4*bg+r.
// Shuffle math verified rounds 2-7 and UNCHANGED. LDS 4-wave reduce ->
// 4 atomics/thread; total 524K adds/pass = proven round-0 contention level.
// ---------------------------------------------------------------------------
__global__ __launch_bounds__(256) void k_route(const uint2* __restrict__ uh,
                                               const float* __restrict__ s0,
                                               const float* __restrict__ s1,
                                               float* __restrict__ tgt,
                                               int it) {
    const int blk = blockIdx.x;
    const int bg = blk >> 5;          // 16 b-groups (b = 4*bg + r)
    const int chunk = blk & 31;       // 32 chunks of 32 n
    const int t = threadIdx.x, wave = t >> 6, l = t & 63;

    // lane offset within one n-slab, in uint4 units (slab = 2048 uint4)
    const int laneoff = ((l >> 4) * 1024 + ((l >> 2) & 3) * 256 + bg * 16 + (l & 3) * 4) >> 1;
    const uint4* base = (const uint4*)uh;
    const int n0 = chunk * 32 + wave * 8;

    float4 vv[4];
    if (it != 0) {
        // recompute v (and v0+v1 for it==2) per b: lane's eo set is 4l..4l+3,
        // exactly the verified mapping -> squash4's e-group shuffles unchanged.
#pragma unroll
        for (int r = 0; r < 4; ++r) {
            const int b = bg * 4 + r;
            float4 v4 = squash4(*(const float4*)(s0 + b * EO_ + 4 * l));
            if (it == 2) {
                float4 v1 = squash4(*(const float4*)(s1 + b * EO_ + 4 * l));
                v4.x += v1.x; v4.y += v1.y; v4.z += v1.z; v4.w += v1.w;
            }
            vv[r] = v4;
        }
    }

    float acc[4][4];
#pragma unroll
    for (int r = 0; r < 4; ++r)
#pragma unroll
        for (int q = 0; q < 4; ++q) acc[r][q] = 0.f;

#pragma unroll
    for (int bb = 0; bb < 2; ++bb) {
        uint4 LA[4][2];
#pragma unroll
        for (int nn = 0; nn < 4; ++nn) {
            const size_t nb = (size_t)(n0 + bb * 4 + nn) * 2048 + laneoff;
            LA[nn][0] = base[nb];
            LA[nn][1] = base[nb + 1];
        }

#pragma unroll
        for (int nn = 0; nn < 4; ++nn) {
            const uint4 L0 = LA[nn][0], L1 = LA[nn][1];
            float x[4][4];   // x[r][q] = u_hat[b=4bg+r][n][4l+q]
            x[0][0] = bf2f(L0.x); x[1][0] = bf2f(L0.x >> 16);
            x[2][0] = bf2f(L0.y); x[3][0] = bf2f(L0.y >> 16);
            x[0][1] = bf2f(L0.z); x[1][1] = bf2f(L0.z >> 16);
            x[2][1] = bf2f(L0.w); x[3][1] = bf2f(L0.w >> 16);
            x[0][2] = bf2f(L1.x); x[1][2] = bf2f(L1.x >> 16);
            x[2][2] = bf2f(L1.y); x[3][2] = bf2f(L1.y >> 16);
            x[0][3] = bf2f(L1.z); x[1][3] = bf2f(L1.z >> 16);
            x[2][3] = bf2f(L1.w); x[3][3] = bf2f(L1.w >> 16);

            float c[4];
            if (it == 0) {
                c[0] = c[1] = c[2] = c[3] = 0.125f;
            } else {
                float lg[4];
#pragma unroll
                for (int r = 0; r < 4; ++r) {
                    float pd = x[r][0] * vv[r].x + x[r][1] * vv[r].y
                             + x[r][2] * vv[r].z + x[r][3] * vv[r].w;
                    pd += __shfl_xor(pd, 1);
                    pd += __shfl_xor(pd, 2);
                    pd += __shfl_xor(pd, 4);        // logit(n, e, b=4bg+r)
                    lg[r] = pd;
                }
                float mx[4];
#pragma unroll
                for (int r = 0; r < 4; ++r) mx[r] = lg[r];
#pragma unroll
                for (int r = 0; r < 4; ++r) mx[r] = fmaxf(mx[r], __shfl_xor(mx[r], 8));
#pragma unroll
                for (int r = 0; r < 4; ++r) mx[r] = fmaxf(mx[r], __shfl_xor(mx[r], 16));
#pragma unroll
                for (int r = 0; r < 4; ++r) mx[r] = fmaxf(mx[r], __shfl_xor(mx[r], 32));
                float ex[4], sm[4];
#pragma unroll
                for (int r = 0; r < 4; ++r) { ex[r] = __expf(lg[r] - mx[r]); sm[r] = ex[r]; }
#pragma unroll
                for (int r = 0; r < 4; ++r) sm[r] += __shfl_xor(sm[r], 8);
#pragma unroll
                for (int r = 0; r < 4; ++r) sm[r] += __shfl_xor(sm[r], 16);
#pragma unroll
                for (int r = 0; r < 4; ++r) sm[r] += __shfl_xor(sm[r], 32);
#pragma unroll
                for (int r = 0; r < 4; ++r) c[r] = ex[r] * __builtin_amdgcn_rcpf(sm[r]);
            }
#pragma unroll
            for (int r = 0; r < 4; ++r)
#pragma unroll
                for (int q = 0; q < 4; ++q)
                    acc[r][q] = fmaf(c[r], x[r][q], acc[r][q]);
        }
    }

    __shared__ __align__(16) float red[4][4][EO_];   // [wave][r][eo] 16 KB
#pragma unroll
    for (int r = 0; r < 4; ++r)
        *(float4*)&red[wave][r][4 * l] = make_float4(acc[r][0], acc[r][1], acc[r][2], acc[r][3]);
    __syncthreads();
#pragma unroll
    for (int r = 0; r < 4; ++r) {
        float v = red[0][r][t] + red[1][r][t] + red[2][r][t] + red[3][r][t];
        atomicAdd(&tgt[(bg * 4 + r) * EO_ + t], v);
    }
}

// ---------------------------------------------------------------------------
// K3: out = squash(s2). 64 blocks x 256 (t = eo; o-group = 32 lanes).
// ---------------------------------------------------------------------------
__global__ __launch_bounds__(256) void k_out(const float* __restrict__ s2,
                                             float* __restrict__ out) {
    const int b = blockIdx.x, t = threadIdx.x;
    float sv = s2[b * EO_ + t];
    float sq = sv * sv;
    sq += __shfl_xor(sq, 1);
    sq += __shfl_xor(sq, 2);
    sq += __shfl_xor(sq, 4);
    sq += __shfl_xor(sq, 8);
    sq += __shfl_xor(sq, 16);
    float nrm = sqrtf(sq);
    out[b * EO_ + t] = sq / ((1.f + sq) * (nrm + 1e-8f)) * sv;
}

extern "C" void kernel_launch(void* const* d_in, const int* in_sizes, int n_in,
                              void* d_out, int out_size, void* d_ws, size_t ws_size,
                              hipStream_t stream) {
    const float* u = (const float*)d_in[0];     // f32 [64,1024,64]
    const float* W = (const float*)d_in[1];     // f32 [1024,8,32,64]
    float* out = (float*)d_out;                 // f32 [64,8,32]

    char* ws = (char*)d_ws;
    uint2* uh = (uint2*)ws;                      // 33,554,432 B  u_hat bf16 (uh2 layout)
    float* s0 = (float*)(ws + 33554432);         // 65,536 B
    float* s1 = s0 + B_ * EO_;                   // contiguous s0|s1|s2 for zeroing
    float* s2 = s1 + B_ * EO_;

    k_uhat <<<dim3(N_),  dim3(256), 0, stream>>>(u, W, uh, s0);
    k_route<<<dim3(512), dim3(256), 0, stream>>>(uh, s0, s1, s0, 0);
    k_route<<<dim3(512), dim3(256), 0, stream>>>(uh, s0, s1, s1, 1);
    k_route<<<dim3(512), dim3(256), 0, stream>>>(uh, s0, s1, s2, 2);
    k_out  <<<dim3(B_),  dim3(256), 0, stream>>>(s2, out);
}